// Round 9
// baseline (723.048 us; speedup 1.0000x reference)
//
#include <hip/hip_runtime.h>
#include <stdint.h>

#define D_MODEL  1024
#define D_HIDDEN 4096
#define NE       8
#define T_TOK    8192
#define BM       128
#define BN       128
#define MAXT     136
#define ROWS_CAP 17408

typedef __attribute__((ext_vector_type(8))) short short8;
typedef __attribute__((ext_vector_type(4))) float f32x4;

__device__ inline uint16_t f2bf(float f) {
  uint32_t u = __float_as_uint(f);
  uint32_t r = (u + 0x7fffu + ((u >> 16) & 1u)) >> 16;
  return (uint16_t)r;
}

#define GLOAD16(gp, lp) __builtin_amdgcn_global_load_lds( \
  (const __attribute__((address_space(1))) uint32_t*)(gp), \
  (__attribute__((address_space(3))) uint32_t*)(lp), 16, 0, 0)

// ------- merged transpose + f32->bf16 convert for W1 and W2 ----------------
// z<8: W1 (R=1024,C=4096) tile (x,y); z>=8: W2 (R=4096,C=1024) remap
// (x,y) -> (x&15, y*4+(x>>4)) so one grid covers both shapes.
__global__ void transpose_cvt2(const float* __restrict__ W1, uint16_t* __restrict__ W1T,
                               const float* __restrict__ W2, uint16_t* __restrict__ W2T) {
  __shared__ float tile[64][65];
  int z = blockIdx.z;
  const float* in; uint16_t* out; int R, C, tx, ty;
  if (z < 8) {
    in = W1 + (size_t)z * D_MODEL * D_HIDDEN; out = W1T + (size_t)z * D_MODEL * D_HIDDEN;
    R = D_MODEL; C = D_HIDDEN; tx = blockIdx.x; ty = blockIdx.y;
  } else {
    in = W2 + (size_t)(z - 8) * D_MODEL * D_HIDDEN; out = W2T + (size_t)(z - 8) * D_MODEL * D_HIDDEN;
    R = D_HIDDEN; C = D_MODEL; tx = blockIdx.x & 15; ty = blockIdx.y * 4 + (blockIdx.x >> 4);
  }
  int c0 = tx * 64, r0 = ty * 64;
  int t = threadIdx.x;
  int lr = t >> 4, lc4 = (t & 15) * 4;
#pragma unroll
  for (int i = 0; i < 4; ++i) {
    int rr = i * 16 + lr;
    float4 v = *(const float4*)(in + (size_t)(r0 + rr) * C + c0 + lc4);
    tile[rr][lc4] = v.x; tile[rr][lc4 + 1] = v.y;
    tile[rr][lc4 + 2] = v.z; tile[rr][lc4 + 3] = v.w;
  }
  __syncthreads();
  int oc = t >> 3, orr = (t & 7) * 8;
#pragma unroll
  for (int i = 0; i < 2; ++i) {
    int cc = i * 32 + oc;
    short8 o;
#pragma unroll
    for (int j = 0; j < 8; ++j) o[j] = (short)f2bf(tile[orr + j][cc]);
    *(short8*)(out + (size_t)(c0 + cc) * R + r0 + orr) = o;
  }
}

// ---------------- router: logits, top-2, weights, expert bucketing ---------
__global__ void router_kernel(const float* __restrict__ x, const float* __restrict__ Wr,
                              const float* __restrict__ br,
                              int* __restrict__ cnt, int* __restrict__ tok_of,
                              int* __restrict__ k_of, float* __restrict__ tok_w) {
  int t = blockIdx.x * 4 + (threadIdx.x >> 6);
  int l = threadIdx.x & 63;
  const float* xr = x + (size_t)t * D_MODEL;
  float a[8] = {0.f,0.f,0.f,0.f,0.f,0.f,0.f,0.f};
  for (int d = l; d < D_MODEL; d += 64) {
    float xv = xr[d];
    const float4* w4 = (const float4*)(Wr + d * 8);
    float4 wa = w4[0], wb = w4[1];
    a[0] += xv * wa.x; a[1] += xv * wa.y; a[2] += xv * wa.z; a[3] += xv * wa.w;
    a[4] += xv * wb.x; a[5] += xv * wb.y; a[6] += xv * wb.z; a[7] += xv * wb.w;
  }
#pragma unroll
  for (int e = 0; e < 8; ++e) {
    float v = a[e];
#pragma unroll
    for (int off = 32; off > 0; off >>= 1) v += __shfl_xor(v, off);
    a[e] = v + br[e];
  }
  if (l == 0) {
    int i1 = 0; float v1 = a[0];
#pragma unroll
    for (int e = 1; e < 8; ++e) if (a[e] > v1) { v1 = a[e]; i1 = e; }
    int i2 = -1; float v2 = -1e30f;
#pragma unroll
    for (int e = 0; e < 8; ++e) if (e != i1 && a[e] > v2) { v2 = a[e]; i2 = e; }
    float e2 = __expf(v2 - v1);
    float inv = 1.0f / (1.0f + e2);
    int p1 = atomicAdd(cnt + i1, 1);
    tok_of[i1 * T_TOK + p1] = t; k_of[i1 * T_TOK + p1] = 0;
    int p2 = atomicAdd(cnt + i2, 1);
    tok_of[i2 * T_TOK + p2] = t; k_of[i2 * T_TOK + p2] = 1;
    tok_w[t * 2 + 0] = inv; tok_w[t * 2 + 1] = e2 * inv;
  }
}

// meta ints: [0]=ntiles, [1..9]=base[0..8], [16..)=tile_e, [16+MAXT..)=tile_row0
__global__ void setup_kernel(const int* __restrict__ cnt, int* __restrict__ meta) {
  int l = threadIdx.x;
  int tiles[8], base[9], tpre[9];
  base[0] = 0; tpre[0] = 0;
#pragma unroll
  for (int e = 0; e < 8; ++e) {
    int c = cnt[e];
    tiles[e] = (c + BM - 1) / BM;
    base[e + 1] = base[e] + tiles[e] * BM;
    tpre[e + 1] = tpre[e] + tiles[e];
  }
  int nt = tpre[8];
  if (l == 0) meta[0] = nt;
  if (l < 9) meta[1 + l] = base[l];
  for (int i = l; i < nt; i += 64) {
    int e = 0;
#pragma unroll
    for (int k = 1; k < 8; ++k) if (i >= tpre[k]) e = k;
    meta[16 + i] = e;
    meta[16 + MAXT + i] = base[e] + (i - tpre[e]) * BM;
  }
}

// ---------------- gather tokens into permuted bf16 buffer ------------------
__global__ void gather_kernel(const float* __restrict__ x, const int* __restrict__ cnt,
                              const int* __restrict__ meta, const int* __restrict__ tok_of,
                              const int* __restrict__ k_of, const float* __restrict__ tok_w,
                              uint16_t* __restrict__ xp,
                              int* __restrict__ row2tok, float* __restrict__ row2w) {
  int r = blockIdx.x * 4 + (threadIdx.x >> 6);
  int l = threadIdx.x & 63;
  int total = meta[9];
  if (r >= total) return;
  int e = 0;
#pragma unroll
  for (int i = 1; i < 8; ++i) if (r >= meta[1 + i]) e = i;
  int p = r - meta[1 + e];
  uint16_t* dst = xp + (size_t)r * D_MODEL + l * 16;
  if (p < cnt[e]) {
    int t = tok_of[e * T_TOK + p];
    if (l == 0) {
      row2tok[r] = t;
      row2w[r] = tok_w[t * 2 + k_of[e * T_TOK + p]];
    }
    const float4* src = (const float4*)(x + (size_t)t * D_MODEL + l * 16);
    short8 o0, o1;
    float4 v0 = src[0], v1 = src[1], v2 = src[2], v3 = src[3];
    o0[0] = (short)f2bf(v0.x); o0[1] = (short)f2bf(v0.y);
    o0[2] = (short)f2bf(v0.z); o0[3] = (short)f2bf(v0.w);
    o0[4] = (short)f2bf(v1.x); o0[5] = (short)f2bf(v1.y);
    o0[6] = (short)f2bf(v1.z); o0[7] = (short)f2bf(v1.w);
    o1[0] = (short)f2bf(v2.x); o1[1] = (short)f2bf(v2.y);
    o1[2] = (short)f2bf(v2.z); o1[3] = (short)f2bf(v2.w);
    o1[4] = (short)f2bf(v3.x); o1[5] = (short)f2bf(v3.y);
    o1[6] = (short)f2bf(v3.z); o1[7] = (short)f2bf(v3.w);
    *(short8*)dst = o0;
    *(short8*)(dst + 8) = o1;
  } else {
    if (l == 0) { row2tok[r] = -1; row2w[r] = 0.f; }
    short8 z = {0,0,0,0,0,0,0,0};
    *(short8*)dst = z;
    *(short8*)(dst + 8) = z;
  }
}

// ---------------- grouped GEMM, 128x128 tile, BK=32, T3-min 2-phase --------
// Double-buffered LDS at SAME total footprint as R8 (2 x 16KB = 32KB; BK
// halved to 32) -> occupancy preserved (up to 5 blocks/CU) AND stage latency
// hidden: per step issue next half-tile's 4 gloads FIRST, then 8 ds_read +
// 16 MFMA on current buf, then one vmcnt(0)+syncthreads (drain lands after
// compute covered the latency). Race-free: buf^1 writes only after the sync
// that ended all reads of buf^1 (previous step's end-of-step sync).
// Grid: R8's XCD-chunked 1-D (FETCH 594->184MB verified).
// Swizzle: 64B rows, 4 segs; seg s of row r at slot s^((r>>1)&3) (R5-verified
// 0-conflict at this row width), source-pre-swizzled (rule #21).
template<int KD, int ND, int NTX, bool FUSED_OUT>
__global__ void moe_gemm(const uint16_t* __restrict__ A, const uint16_t* __restrict__ Bt,
                         const float* __restrict__ bias,
                         uint16_t* __restrict__ Cb, float* __restrict__ out,
                         const int* __restrict__ row2tok, const float* __restrict__ row2w,
                         const int* __restrict__ meta) {
  int nt = meta[0];
  int d = blockIdx.x;
  int xcd = d & 7, q = d >> 3;
  int mt = xcd * (MAXT / 8) + q / NTX;
  if (mt >= nt) return;
  int n0 = (q % NTX) * BN;
  int e = meta[16 + mt];
  int row0 = meta[16 + MAXT + mt];

  __shared__ __align__(16) uint16_t L[16384];   // 32 KB: 2 bufs x (A 8K | B 8K)

  int t = threadIdx.x;
  int w = t >> 6, l = t & 63;
  int wr = (w >> 1) * 64, wc = (w & 1) * 64;

  const uint16_t* Ab = A + (size_t)row0 * KD;
  const uint16_t* Bb = Bt + ((size_t)e * ND + n0) * KD;

  f32x4 acc[4][4];
#pragma unroll
  for (int m = 0; m < 4; ++m)
#pragma unroll
    for (int n = 0; n < 4; ++n) acc[m][n] = (f32x4){0.f, 0.f, 0.f, 0.f};

  int srow = t >> 2;                                  // stage row 0..63
  int sseg = ((t & 3) ^ ((srow >> 1) & 3)) * 8;       // pre-swizzled source seg
  int koff = ((l >> 4) ^ (((l & 15) >> 1) & 3)) * 8;  // swizzled read seg

  auto stage = [&](int buf, int kt) {
    const uint16_t* ga = Ab + kt * 32;
    const uint16_t* gb = Bb + kt * 32;
    uint16_t* ld = L + buf * 8192;
    GLOAD16(ga + (size_t)srow * KD + sseg, ld + t * 8);
    GLOAD16(ga + (size_t)(srow + 64) * KD + sseg, ld + 2048 + t * 8);
    GLOAD16(gb + (size_t)srow * KD + sseg, ld + 4096 + t * 8);
    GLOAD16(gb + (size_t)(srow + 64) * KD + sseg, ld + 6144 + t * 8);
  };

  constexpr int NS = KD / 32;
  stage(0, 0);
  asm volatile("s_waitcnt vmcnt(0)" ::: "memory");
  __syncthreads();

  for (int s = 0; s < NS; ++s) {
    int cur = s & 1;
    if (s + 1 < NS) stage(cur ^ 1, s + 1);
    const uint16_t* la = L + cur * 8192;
    const uint16_t* lb = la + 4096;
    short8 af[4], bf[4];
#pragma unroll
    for (int m = 0; m < 4; ++m)
      af[m] = *(const short8*)(la + (wr + m * 16 + (l & 15)) * 32 + koff);
#pragma unroll
    for (int n = 0; n < 4; ++n)
      bf[n] = *(const short8*)(lb + (wc + n * 16 + (l & 15)) * 32 + koff);
#pragma unroll
    for (int m = 0; m < 4; ++m)
#pragma unroll
      for (int n = 0; n < 4; ++n)
        acc[m][n] = __builtin_amdgcn_mfma_f32_16x16x32_bf16(af[m], bf[n], acc[m][n], 0, 0, 0);
    if (s + 1 < NS) {
      asm volatile("s_waitcnt vmcnt(0)" ::: "memory");
      __syncthreads();
    }
  }

  // ---------------- epilogue ----------------
  if (!FUSED_OUT) {
#pragma unroll
    for (int m = 0; m < 4; ++m) {
      int row_b = row0 + wr + m * 16 + (l >> 4) * 4;
#pragma unroll
      for (int n = 0; n < 4; ++n) {
        int col = n0 + wc + n * 16 + (l & 15);
        float bv = bias[e * ND + col];
#pragma unroll
        for (int r = 0; r < 4; ++r)
          Cb[(size_t)(row_b + r) * ND + col] = f2bf(fmaxf(acc[m][n][r] + bv, 0.f));
      }
    }
  } else {
    float bv[4];
#pragma unroll
    for (int n = 0; n < 4; ++n)
      bv[n] = bias[e * ND + n0 + wc + n * 16 + (l & 15)];
#pragma unroll
    for (int m = 0; m < 4; ++m) {
#pragma unroll
      for (int r = 0; r < 4; ++r) {
        int grow = row0 + wr + m * 16 + (l >> 4) * 4 + r;
        int tok = row2tok[grow];
        float wgt = row2w[grow];
        if (tok >= 0) {
#pragma unroll
          for (int n = 0; n < 4; ++n) {
            int col = n0 + wc + n * 16 + (l & 15);
            atomicAdd(out + (size_t)tok * ND + col, wgt * (acc[m][n][r] + bv[n]));
          }
        }
      }
    }
  }
}

extern "C" void kernel_launch(void* const* d_in, const int* in_sizes, int n_in,
                              void* d_out, int out_size, void* d_ws, size_t ws_size,
                              hipStream_t stream) {
  const float* x  = (const float*)d_in[0];
  const float* Wr = (const float*)d_in[1];
  const float* br = (const float*)d_in[2];
  const float* W1 = (const float*)d_in[3];
  const float* b1 = (const float*)d_in[4];
  const float* W2 = (const float*)d_in[5];
  const float* b2 = (const float*)d_in[6];
  float* out = (float*)d_out;

  char* ws = (char*)d_ws;
  size_t off = 0;
  auto alloc = [&](size_t bytes) -> void* {
    void* p = ws + off;
    off += (bytes + 255) & ~(size_t)255;
    return p;
  };
  uint16_t* W1T    = (uint16_t*)alloc((size_t)NE * D_MODEL * D_HIDDEN * 2);
  uint16_t* W2T    = (uint16_t*)alloc((size_t)NE * D_MODEL * D_HIDDEN * 2);
  uint16_t* xp     = (uint16_t*)alloc((size_t)ROWS_CAP * D_MODEL * 2);
  uint16_t* hp     = (uint16_t*)alloc((size_t)ROWS_CAP * D_HIDDEN * 2);
  int*      cnt    = (int*)alloc(NE * 4);
  int*      tok_of = (int*)alloc((size_t)NE * T_TOK * 4);
  int*      k_of   = (int*)alloc((size_t)NE * T_TOK * 4);
  float*    tok_w  = (float*)alloc(T_TOK * 2 * 4);
  int*      row2tok= (int*)alloc(ROWS_CAP * 4);
  float*    row2w  = (float*)alloc(ROWS_CAP * 4);
  int*      meta   = (int*)alloc((16 + 2 * MAXT) * 4);

  if (ws_size < off) return;  // workspace too small: visible failure

  hipMemsetAsync(cnt, 0, NE * 4, stream);
  hipMemsetAsync(out, 0, (size_t)out_size * 4, stream);
  transpose_cvt2<<<dim3(64, 16, 16), 256, 0, stream>>>(W1, W1T, W2, W2T);
  router_kernel<<<T_TOK / 4, 256, 0, stream>>>(x, Wr, br, cnt, tok_of, k_of, tok_w);
  setup_kernel<<<1, 64, 0, stream>>>(cnt, meta);
  gather_kernel<<<ROWS_CAP / 4, 256, 0, stream>>>(x, cnt, meta, tok_of, k_of, tok_w,
                                                  xp, row2tok, row2w);
  moe_gemm<D_MODEL, D_HIDDEN, 32, false><<<MAXT * 32, 256, 0, stream>>>(
      xp, W1T, b1, hp, nullptr, nullptr, nullptr, meta);
  moe_gemm<D_HIDDEN, D_MODEL, 8, true><<<MAXT * 8, 256, 0, stream>>>(
      hp, W2T, b2, nullptr, out, row2tok, row2w, meta);
}

// Round 10
// 688.793 us; speedup vs baseline: 1.0497x; 1.0497x over previous
//
#include <hip/hip_runtime.h>
#include <stdint.h>

#define D_MODEL  1024
#define D_HIDDEN 4096
#define NE       8
#define T_TOK    8192
#define BM       128
#define BN       128
#define BK       64
#define MAXT     136
#define ROWS_CAP 17408

typedef __attribute__((ext_vector_type(8))) short short8;
typedef __attribute__((ext_vector_type(4))) float f32x4;

__device__ inline uint16_t f2bf(float f) {
  uint32_t u = __float_as_uint(f);
  uint32_t r = (u + 0x7fffu + ((u >> 16) & 1u)) >> 16;
  return (uint16_t)r;
}

#define GLOAD16(gp, lp) __builtin_amdgcn_global_load_lds( \
  (const __attribute__((address_space(1))) uint32_t*)(gp), \
  (__attribute__((address_space(3))) uint32_t*)(lp), 16, 0, 0)

// Register-resident expert tile table from cnt[8]: padded row bases and the
// (expert, row0) of tile mt. Replaces the setup_kernel/meta round-trip.
__device__ inline int tile_table(const int* __restrict__ cnt, int mt,
                                 int& e, int& row0, int& total_rows) {
  int base = 0, tp = 0;
  e = 0; row0 = 0;
#pragma unroll
  for (int k = 0; k < 8; ++k) {
    int tiles = (cnt[k] + BM - 1) >> 7;
    if (mt >= tp && mt < tp + tiles) { e = k; row0 = base + (mt - tp) * BM; }
    tp += tiles; base += tiles * BM;
  }
  total_rows = base;
  return tp;   // ntiles
}

// ---------------- transpose + f32->bf16 convert: in [R][C] -> out [C][R] ----
__global__ void transpose_cvt(const float* __restrict__ in, uint16_t* __restrict__ out,
                              int R, int C) {
  __shared__ float tile[64][65];
  size_t eoff = (size_t)blockIdx.z * R * C;
  int c0 = blockIdx.x * 64, r0 = blockIdx.y * 64;
  int t = threadIdx.x;
  int lr = t >> 4, lc4 = (t & 15) * 4;
#pragma unroll
  for (int i = 0; i < 4; ++i) {
    int rr = i * 16 + lr;
    float4 v = *(const float4*)(in + eoff + (size_t)(r0 + rr) * C + c0 + lc4);
    tile[rr][lc4] = v.x; tile[rr][lc4 + 1] = v.y;
    tile[rr][lc4 + 2] = v.z; tile[rr][lc4 + 3] = v.w;
  }
  __syncthreads();
  int oc = t >> 3, orr = (t & 7) * 8;
#pragma unroll
  for (int i = 0; i < 2; ++i) {
    int cc = i * 32 + oc;
    short8 o;
#pragma unroll
    for (int j = 0; j < 8; ++j) o[j] = (short)f2bf(tile[orr + j][cc]);
    *(short8*)(out + eoff + (size_t)(c0 + cc) * R + r0 + orr) = o;
  }
}

// ---------------- router: logits, top-2, weights, expert bucketing ---------
__global__ void router_kernel(const float* __restrict__ x, const float* __restrict__ Wr,
                              const float* __restrict__ br,
                              int* __restrict__ cnt, int* __restrict__ tok_of,
                              int* __restrict__ k_of, float* __restrict__ tok_w) {
  int t = blockIdx.x * 4 + (threadIdx.x >> 6);
  int l = threadIdx.x & 63;
  const float* xr = x + (size_t)t * D_MODEL;
  float a[8] = {0.f,0.f,0.f,0.f,0.f,0.f,0.f,0.f};
  for (int d = l; d < D_MODEL; d += 64) {
    float xv = xr[d];
    const float4* w4 = (const float4*)(Wr + d * 8);
    float4 wa = w4[0], wb = w4[1];
    a[0] += xv * wa.x; a[1] += xv * wa.y; a[2] += xv * wa.z; a[3] += xv * wa.w;
    a[4] += xv * wb.x; a[5] += xv * wb.y; a[6] += xv * wb.z; a[7] += xv * wb.w;
  }
#pragma unroll
  for (int e = 0; e < 8; ++e) {
    float v = a[e];
#pragma unroll
    for (int off = 32; off > 0; off >>= 1) v += __shfl_xor(v, off);
    a[e] = v + br[e];
  }
  if (l == 0) {
    int i1 = 0; float v1 = a[0];
#pragma unroll
    for (int e = 1; e < 8; ++e) if (a[e] > v1) { v1 = a[e]; i1 = e; }
    int i2 = -1; float v2 = -1e30f;
#pragma unroll
    for (int e = 0; e < 8; ++e) if (e != i1 && a[e] > v2) { v2 = a[e]; i2 = e; }
    float e2 = __expf(v2 - v1);
    float inv = 1.0f / (1.0f + e2);
    int p1 = atomicAdd(cnt + i1, 1);
    tok_of[i1 * T_TOK + p1] = t; k_of[i1 * T_TOK + p1] = 0;
    int p2 = atomicAdd(cnt + i2, 1);
    tok_of[i2 * T_TOK + p2] = t; k_of[i2 * T_TOK + p2] = 1;
    tok_w[t * 2 + 0] = inv; tok_w[t * 2 + 1] = e2 * inv;
  }
}

// ---------------- gather tokens into permuted bf16 buffer ------------------
__global__ void gather_kernel(const float* __restrict__ x, const int* __restrict__ cnt,
                              const int* __restrict__ tok_of,
                              const int* __restrict__ k_of, const float* __restrict__ tok_w,
                              uint16_t* __restrict__ xp,
                              int* __restrict__ row2tok, float* __restrict__ row2w) {
  int r = blockIdx.x * 4 + (threadIdx.x >> 6);
  int l = threadIdx.x & 63;
  // register-resident base table
  int base[9];
  base[0] = 0;
#pragma unroll
  for (int k = 0; k < 8; ++k)
    base[k + 1] = base[k] + (((cnt[k] + BM - 1) >> 7) << 7);
  if (r >= base[8]) return;
  int e = 0;
#pragma unroll
  for (int i = 1; i < 8; ++i) if (r >= base[i]) e = i;
  int p = r - base[e];
  uint16_t* dst = xp + (size_t)r * D_MODEL + l * 16;
  if (p < cnt[e]) {
    int t = tok_of[e * T_TOK + p];
    if (l == 0) {
      row2tok[r] = t;
      row2w[r] = tok_w[t * 2 + k_of[e * T_TOK + p]];
    }
    const float4* src = (const float4*)(x + (size_t)t * D_MODEL + l * 16);
    short8 o0, o1;
    float4 v0 = src[0], v1 = src[1], v2 = src[2], v3 = src[3];
    o0[0] = (short)f2bf(v0.x); o0[1] = (short)f2bf(v0.y);
    o0[2] = (short)f2bf(v0.z); o0[3] = (short)f2bf(v0.w);
    o0[4] = (short)f2bf(v1.x); o0[5] = (short)f2bf(v1.y);
    o0[6] = (short)f2bf(v1.z); o0[7] = (short)f2bf(v1.w);
    o1[0] = (short)f2bf(v2.x); o1[1] = (short)f2bf(v2.y);
    o1[2] = (short)f2bf(v2.z); o1[3] = (short)f2bf(v2.w);
    o1[4] = (short)f2bf(v3.x); o1[5] = (short)f2bf(v3.y);
    o1[6] = (short)f2bf(v3.z); o1[7] = (short)f2bf(v3.w);
    *(short8*)dst = o0;
    *(short8*)(dst + 8) = o1;
  } else {
    if (l == 0) { row2tok[r] = -1; row2w[r] = 0.f; }
    short8 z = {0,0,0,0,0,0,0,0};
    *(short8*)dst = z;
    *(short8*)(dst + 8) = z;
  }
}

// ---------------- grouped GEMM, 128x128 tile, BK=64 (R8 measured-best) -----
// Single 32KB LDS buffer, gload_lds width-16 staging, vmcnt(0)+syncthreads
// per K-step (pipelined variants all measured slower: R3/R4/R7/R9).
// Grid: XCD-chunked 1-D (FETCH 594->184MB verified): d -> xcd=d&7, q=d>>3;
// mt = xcd*(MAXT/8)+q/NTX, n0=(q%NTX)*BN.
// Swizzle (T2, verified 0-conflict): elem col -> slot col^((row&7)<<3),
// source-pre-swizzled (rule #21), same XOR on reads.
template<int KD, int ND, int NTX, bool FUSED_OUT>
__global__ void moe_gemm(const uint16_t* __restrict__ A, const uint16_t* __restrict__ Bt,
                         const float* __restrict__ bias,
                         uint16_t* __restrict__ Cb, float* __restrict__ out,
                         const int* __restrict__ row2tok, const float* __restrict__ row2w,
                         const int* __restrict__ cnt) {
  int d = blockIdx.x;
  int xcd = d & 7, q = d >> 3;
  int mt = xcd * (MAXT / 8) + q / NTX;
  int e, row0, total_rows;
  int nt = tile_table(cnt, mt, e, row0, total_rows);
  if (mt >= nt) return;
  int n0 = (q % NTX) * BN;

  __shared__ __align__(16) uint16_t lA[BM * BK];
  __shared__ __align__(16) uint16_t lB[BN * BK];

  int t = threadIdx.x;
  int w = t >> 6, l = t & 63;
  int wr = (w >> 1) * 64, wc = (w & 1) * 64;

  const uint16_t* Ab = A + (size_t)row0 * KD;
  const uint16_t* Bb = Bt + ((size_t)e * ND + n0) * KD;

  f32x4 acc[4][4];
#pragma unroll
  for (int m = 0; m < 4; ++m)
#pragma unroll
    for (int n = 0; n < 4; ++n) acc[m][n] = (f32x4){0.f, 0.f, 0.f, 0.f};

  int trow = t >> 3;                        // 0..31
  int tcol = (t & 7) * 8;                   // linear LDS k-elem offset
  int scol = tcol ^ ((trow & 7) << 3);      // swizzled global k-elem offset

  for (int kt = 0; kt < KD / BK; ++kt) {
    int k0 = kt * BK;
    __syncthreads();
#pragma unroll
    for (int i = 0; i < 4; ++i) {
      GLOAD16(Ab + (size_t)(i * 32 + trow) * KD + k0 + scol, lA + (i * 32 + trow) * BK + tcol);
      GLOAD16(Bb + (size_t)(i * 32 + trow) * KD + k0 + scol, lB + (i * 32 + trow) * BK + tcol);
    }
    asm volatile("s_waitcnt vmcnt(0)" ::: "memory");
    __syncthreads();
#pragma unroll
    for (int kk = 0; kk < 2; ++kk) {
      short8 af[4], bf[4];
      int ko = kk * 32 + (l >> 4) * 8;
      int sw = ((l & 7) << 3);
#pragma unroll
      for (int m = 0; m < 4; ++m)
        af[m] = *(const short8*)(lA + (wr + m * 16 + (l & 15)) * BK + (ko ^ sw));
#pragma unroll
      for (int n = 0; n < 4; ++n)
        bf[n] = *(const short8*)(lB + (wc + n * 16 + (l & 15)) * BK + (ko ^ sw));
#pragma unroll
      for (int m = 0; m < 4; ++m)
#pragma unroll
        for (int n = 0; n < 4; ++n)
          acc[m][n] = __builtin_amdgcn_mfma_f32_16x16x32_bf16(af[m], bf[n], acc[m][n], 0, 0, 0);
    }
  }

  // ---------------- epilogue ----------------
  if (!FUSED_OUT) {
#pragma unroll
    for (int m = 0; m < 4; ++m) {
      int row_b = row0 + wr + m * 16 + (l >> 4) * 4;
#pragma unroll
      for (int n = 0; n < 4; ++n) {
        int col = n0 + wc + n * 16 + (l & 15);
        float bv = bias[e * ND + col];
#pragma unroll
        for (int r = 0; r < 4; ++r)
          Cb[(size_t)(row_b + r) * ND + col] = f2bf(fmaxf(acc[m][n][r] + bv, 0.f));
      }
    }
  } else {
    float bv[4];
#pragma unroll
    for (int n = 0; n < 4; ++n)
      bv[n] = bias[e * ND + n0 + wc + n * 16 + (l & 15)];
#pragma unroll
    for (int m = 0; m < 4; ++m) {
#pragma unroll
      for (int r = 0; r < 4; ++r) {
        int grow = row0 + wr + m * 16 + (l >> 4) * 4 + r;
        int tok = row2tok[grow];
        float wgt = row2w[grow];
        if (tok >= 0) {
#pragma unroll
          for (int n = 0; n < 4; ++n) {
            int col = n0 + wc + n * 16 + (l & 15);
            atomicAdd(out + (size_t)tok * ND + col, wgt * (acc[m][n][r] + bv[n]));
          }
        }
      }
    }
  }
}

extern "C" void kernel_launch(void* const* d_in, const int* in_sizes, int n_in,
                              void* d_out, int out_size, void* d_ws, size_t ws_size,
                              hipStream_t stream) {
  const float* x  = (const float*)d_in[0];
  const float* Wr = (const float*)d_in[1];
  const float* br = (const float*)d_in[2];
  const float* W1 = (const float*)d_in[3];
  const float* b1 = (const float*)d_in[4];
  const float* W2 = (const float*)d_in[5];
  const float* b2 = (const float*)d_in[6];
  float* out = (float*)d_out;

  char* ws = (char*)d_ws;
  size_t off = 0;
  auto alloc = [&](size_t bytes) -> void* {
    void* p = ws + off;
    off += (bytes + 255) & ~(size_t)255;
    return p;
  };
  uint16_t* W1T    = (uint16_t*)alloc((size_t)NE * D_MODEL * D_HIDDEN * 2);
  uint16_t* W2T    = (uint16_t*)alloc((size_t)NE * D_MODEL * D_HIDDEN * 2);
  uint16_t* xp     = (uint16_t*)alloc((size_t)ROWS_CAP * D_MODEL * 2);
  uint16_t* hp     = (uint16_t*)alloc((size_t)ROWS_CAP * D_HIDDEN * 2);
  int*      cnt    = (int*)alloc(NE * 4);
  int*      tok_of = (int*)alloc((size_t)NE * T_TOK * 4);
  int*      k_of   = (int*)alloc((size_t)NE * T_TOK * 4);
  float*    tok_w  = (float*)alloc(T_TOK * 2 * 4);
  int*      row2tok= (int*)alloc(ROWS_CAP * 4);
  float*    row2w  = (float*)alloc(ROWS_CAP * 4);

  if (ws_size < off) return;  // workspace too small: visible failure

  hipMemsetAsync(cnt, 0, NE * 4, stream);
  hipMemsetAsync(out, 0, (size_t)out_size * 4, stream);
  transpose_cvt<<<dim3(D_HIDDEN / 64, D_MODEL / 64, NE), 256, 0, stream>>>(
      W1, W1T, D_MODEL, D_HIDDEN);
  transpose_cvt<<<dim3(D_MODEL / 64, D_HIDDEN / 64, NE), 256, 0, stream>>>(
      W2, W2T, D_HIDDEN, D_MODEL);
  router_kernel<<<T_TOK / 4, 256, 0, stream>>>(x, Wr, br, cnt, tok_of, k_of, tok_w);
  gather_kernel<<<ROWS_CAP / 4, 256, 0, stream>>>(x, cnt, tok_of, k_of, tok_w,
                                                  xp, row2tok, row2w);
  moe_gemm<D_MODEL, D_HIDDEN, 32, false><<<MAXT * 32, 256, 0, stream>>>(
      xp, W1T, b1, hp, nullptr, nullptr, nullptr, cnt);
  moe_gemm<D_HIDDEN, D_MODEL, 8, true><<<MAXT * 8, 256, 0, stream>>>(
      hp, W2T, b2, nullptr, out, row2tok, row2w, cnt);
}